// Round 16
// baseline (137.874 us; speedup 1.0000x reference)
//
#include <hip/hip_runtime.h>
#include <hip/hip_bf16.h>

// B=8, F=4, T=S=1024, C=32, C2=64, NH=2, HD=16
// Inputs fp32, output fp32. k/v staged bf16 in ws; q stays in LDS (fused).
#define T_LEN 1024

typedef __attribute__((ext_vector_type(8))) short short8;   // 8 bf16 = 4 VGPR
typedef __attribute__((ext_vector_type(4))) short short4v;
typedef __attribute__((ext_vector_type(4))) float float4v;

__device__ __forceinline__ float gelu_exact(float x) {
    return 0.5f * x * (1.0f + erff(x * 0.70710678118654752440f));
}
__device__ __forceinline__ unsigned short f2bf(float f) {   // RNE
    unsigned u = __float_as_uint(f);
    u += 0x7fffu + ((u >> 16) & 1u);
    return (unsigned short)(u >> 16);
}
__device__ __forceinline__ unsigned pk2bf(float a, float b) {  // (lo=a, hi=b)
    __hip_bfloat162 h = __float22bfloat162_rn(make_float2(a, b));
    unsigned u;
    __builtin_memcpy(&u, &h, 4);
    return u;
}

// ---------------------------------------------------------------------------
// kv_tcl: k/v TCL, 512 blocks x 256 thr, 32-row tiles.
// [0,256): k -> kbf [8][1024][32]; [256,512): v -> vtbf [8][2][16][1024]
// with PV-perm s-order inside each 32-block: slot kp holds s-offset o where
// kp = (r>>2)<<3 | hi<<2 | (r&3), hi=o>>4, r=o&15  (bijection). This makes
// the attention PV A-frag (k'=8q+j <-> s-off j<4 ? 4q+j : 16+4q+j-4) equal
// to the lane's OWN QK output registers -> zero cross-lane P movement.
// ---------------------------------------------------------------------------
__global__ __launch_bounds__(256) void kv_tcl(
    const float* __restrict__ pkv,
    const float* __restrict__ wkc, const float* __restrict__ bkc,
    const float* __restrict__ wkp, const float* __restrict__ bkp,
    const float* __restrict__ wvc, const float* __restrict__ bvc,
    const float* __restrict__ wvp, const float* __restrict__ bvp,
    unsigned short* __restrict__ kbf, unsigned short* __restrict__ vtbf)
{
    __shared__ __align__(16) unsigned short Abuf[32 * 96];
    __shared__ __align__(16) unsigned short WbT[64 * 96];
    __shared__ __align__(16) unsigned short Hb[32 * 72];
    __shared__ __align__(16) unsigned short WpB[32 * 72];

    const int tid = threadIdx.x;
    const int gb = blockIdx.x;

    const float *wc, *bc, *wp, *bp;
    unsigned short* outb;
    int n, mode;
    if (gb < 256) { n = gb >> 5;         wc = wkc; bc = bkc; wp = wkp; bp = bkp; outb = kbf;  mode = 0; }
    else          { n = (gb - 256) >> 5; wc = wvc; bc = bvc; wp = wvp; bp = bvp; outb = vtbf; mode = 1; }
    const int t0 = (gb & 31) * 32;

#pragma unroll
    for (int it = 0; it < 3; ++it) {
        int s = (tid + it * 256) >> 3;
        int sub = tid & 7;
        int t = s / 3, tap = s - t * 3;
        int tau = t0 + t - 2 + tap;
        float4 xv = make_float4(0.f, 0.f, 0.f, 0.f);
        if (tau >= 0) xv = *(const float4*)&pkv[((size_t)n * T_LEN + tau) * 32 + sub * 4];
        short4v pk = { (short)f2bf(xv.x), (short)f2bf(xv.y),
                       (short)f2bf(xv.z), (short)f2bf(xv.w) };
        *(short4v*)&Abuf[t * 96 + tap * 32 + sub * 4] = pk;
    }
#pragma unroll
    for (int it = 0; it < 6; ++it) {
        int i4 = tid + it * 256;
        int idx = i4 * 4;
        int o = idx / 96, r = idx - o * 96;
        float4 w4 = *(const float4*)&wc[idx];
        float we[4] = { w4.x, w4.y, w4.z, w4.w };
#pragma unroll
        for (int e = 0; e < 4; ++e) {
            int re = r + e, c = re / 3, tap = re - c * 3;
            WbT[o * 96 + tap * 32 + c] = f2bf(we[e]);
        }
    }
#pragma unroll
    for (int it = 0; it < 2; ++it) {
        int i4 = tid + it * 256;
        int idx = i4 * 4;
        int c = idx >> 6, o = idx & 63;
        float4 w4 = *(const float4*)&wp[idx];
        short4v pk = { (short)f2bf(w4.x), (short)f2bf(w4.y),
                       (short)f2bf(w4.z), (short)f2bf(w4.w) };
        *(short4v*)&WpB[c * 72 + o] = pk;
    }

    const int w = tid >> 6;
    const int ln = tid & 63;
    const int sn = ln & 15;
    const int quad = ln >> 4;

    const float bcv = bc[w * 16 + sn];
    const int tmw = w & 1, cnw = w >> 1;
    const float bpv = bp[cnw * 16 + sn];

    __syncthreads();

    short8 b0 = *(const short8*)&WbT[(w * 16 + sn) * 96 + 0  + quad * 8];
    short8 b1 = *(const short8*)&WbT[(w * 16 + sn) * 96 + 32 + quad * 8];
    short8 b2 = *(const short8*)&WbT[(w * 16 + sn) * 96 + 64 + quad * 8];
    float4v zero = { 0.f, 0.f, 0.f, 0.f };
    float4v acc[2] = { zero, zero };
#pragma unroll
    for (int tm = 0; tm < 2; ++tm) {
        const unsigned short* ar = &Abuf[(tm * 16 + sn) * 96 + quad * 8];
        short8 a0 = *(const short8*)(ar + 0);
        short8 a1 = *(const short8*)(ar + 32);
        short8 a2 = *(const short8*)(ar + 64);
        acc[tm] = __builtin_amdgcn_mfma_f32_16x16x32_bf16(a0, b0, acc[tm], 0, 0, 0);
        acc[tm] = __builtin_amdgcn_mfma_f32_16x16x32_bf16(a1, b1, acc[tm], 0, 0, 0);
        acc[tm] = __builtin_amdgcn_mfma_f32_16x16x32_bf16(a2, b2, acc[tm], 0, 0, 0);
    }
#pragma unroll
    for (int tm = 0; tm < 2; ++tm) {
        float ge[4];
        ge[0] = gelu_exact(acc[tm].x + bcv);
        ge[1] = gelu_exact(acc[tm].y + bcv);
        ge[2] = gelu_exact(acc[tm].z + bcv);
        ge[3] = gelu_exact(acc[tm].w + bcv);
#pragma unroll
        for (int i = 0; i < 4; ++i)
            Hb[(tm * 16 + quad * 4 + i) * 72 + w * 16 + sn] = f2bf(ge[i]);
    }

    __syncthreads();

    const unsigned short* hr = &Hb[(tmw * 16 + sn) * 72 + quad * 8];
    short8 pa0 = *(const short8*)(hr + 0);
    short8 pa1 = *(const short8*)(hr + 32);
    short8 pb0 = *(const short8*)&WpB[(cnw * 16 + sn) * 72 + quad * 8];
    short8 pb1 = *(const short8*)&WpB[(cnw * 16 + sn) * 72 + 32 + quad * 8];
    float4v pacc = zero;
    pacc = __builtin_amdgcn_mfma_f32_16x16x32_bf16(pa0, pb0, pacc, 0, 0, 0);
    pacc = __builtin_amdgcn_mfma_f32_16x16x32_bf16(pa1, pb1, pacc, 0, 0, 0);

    float v[4] = { pacc.x + bpv, pacc.y + bpv, pacc.z + bpv, pacc.w + bpv };
#pragma unroll
    for (int i = 0; i < 4; ++i) {
        int t = tmw * 16 + quad * 4 + i;      // 0..31
        int c = cnw * 16 + sn;
        if (mode == 0) {
            outb[((size_t)n * T_LEN + t0 + t) * 32 + c] = f2bf(v[i]);
        } else {
            int hi = t >> 4, r = t & 15;
            int kp = ((r >> 2) << 3) | (hi << 2) | (r & 3);
            outb[((size_t)(n * 2 + cnw) * 16 + sn) * T_LEN + t0 + kp] = f2bf(v[i]);
        }
    }
}

// ---------------------------------------------------------------------------
// fused_qae v4: 512 blocks x 512 thr. Attention inner loop has ZERO LDS ops:
// QK computed as S^T = K.Q^T (operand swap; d-padding zeros live in B=q so
// unmasked K loads are safe). C output lane(q,sn) = P[t=sn][s=chunk+4q+i] --
// exactly the PV A-frag slots under the perm baked into vtbf. P packs
// in-register (4 pk2bf / 32-s); l is ONE accumulator/lane (t=sn), reduced
// once after the loop (xor16+xor32 + 4 bpermutes to re-index by C-row).
// ---------------------------------------------------------------------------
__global__ __launch_bounds__(512) void fused_qae(
    const float* __restrict__ cd,
    const float* __restrict__ wqc, const float* __restrict__ bqc,
    const float* __restrict__ wqp, const float* __restrict__ bqp,
    const unsigned short* __restrict__ kbf,
    const unsigned short* __restrict__ vtbf,
    const float* __restrict__ wcp, const float* __restrict__ lnw,
    const float* __restrict__ wfc, const float* __restrict__ wmp,
    float* __restrict__ out)
{
    __shared__ __align__(16) char smem[43520];
    unsigned short* Abuf = (unsigned short*)(smem);
    unsigned short* WbT  = (unsigned short*)(smem + 12288);
    unsigned short* Hb   = (unsigned short*)(smem + 24576);
    unsigned short* WpB  = (unsigned short*)(smem + 33792);
    unsigned short* qs   = (unsigned short*)(smem + 38400);

    const int tid = threadIdx.x;
    const int bf = blockIdx.x >> 4;
    const int tt = blockIdx.x & 15;
    const int t0 = tt * 64;
    const int b = bf >> 2;
    const float SC = 0.36067376022224085f;    // 0.25 * log2(e)

    // ---- phase A staging (512 threads)
#pragma unroll
    for (int it = 0; it < 3; ++it) {
        int idx = tid + it * 512;             // 0..1535
        int s = idx >> 3;                     // 0..191
        int sub = idx & 7;
        int t = s / 3, tap = s - t * 3;
        int tau = t0 + t - 2 + tap;
        float4 xv = make_float4(0.f, 0.f, 0.f, 0.f);
        if (tau >= 0) xv = *(const float4*)&cd[((size_t)bf * T_LEN + tau) * 32 + sub * 4];
        short4v pk = { (short)f2bf(xv.x), (short)f2bf(xv.y),
                       (short)f2bf(xv.z), (short)f2bf(xv.w) };
        *(short4v*)&Abuf[t * 96 + tap * 32 + sub * 4] = pk;
    }
#pragma unroll
    for (int it = 0; it < 3; ++it) {
        int i4 = tid + it * 512;              // 0..1535
        int idx = i4 * 4;
        int o = idx / 96, r = idx - o * 96;
        float4 w4 = *(const float4*)&wqc[idx];
        float we[4] = { w4.x, w4.y, w4.z, w4.w };
#pragma unroll
        for (int e = 0; e < 4; ++e) {
            int re = r + e, c = re / 3, tap = re - c * 3;
            WbT[o * 96 + tap * 32 + c] = f2bf(we[e]);
        }
    }
    {
        int idx = tid * 4;                    // 512 float4s
        int c = idx >> 6, o = idx & 63;
        float4 w4 = *(const float4*)&wqp[idx];
        short4v pk = { (short)f2bf(w4.x), (short)f2bf(w4.y),
                       (short)f2bf(w4.z), (short)f2bf(w4.w) };
        *(short4v*)&WpB[c * 72 + o] = pk;
    }

    const int w = tid >> 6;       // wave 0..7
    const int ln = tid & 63;
    const int sn = ln & 15;
    const int quad = ln >> 4;
    const float4v zero = { 0.f, 0.f, 0.f, 0.f };

    __syncthreads();

    // ---- phase A conv GEMM: wave w -> t-tile w&3, o-tiles {w>>2, w>>2+2}
    {
        const int tm = w & 3;
        const int on0 = w >> 2, on1 = on0 + 2;
        const unsigned short* ar = &Abuf[(tm * 16 + sn) * 96 + quad * 8];
        short8 a0 = *(const short8*)(ar + 0);
        short8 a1 = *(const short8*)(ar + 32);
        short8 a2 = *(const short8*)(ar + 64);
        const unsigned short* br0 = &WbT[(on0 * 16 + sn) * 96 + quad * 8];
        const unsigned short* br1 = &WbT[(on1 * 16 + sn) * 96 + quad * 8];
        float4v c0 = zero, c1 = zero;
        c0 = __builtin_amdgcn_mfma_f32_16x16x32_bf16(a0, *(const short8*)(br0 + 0),  c0, 0, 0, 0);
        c0 = __builtin_amdgcn_mfma_f32_16x16x32_bf16(a1, *(const short8*)(br0 + 32), c0, 0, 0, 0);
        c0 = __builtin_amdgcn_mfma_f32_16x16x32_bf16(a2, *(const short8*)(br0 + 64), c0, 0, 0, 0);
        c1 = __builtin_amdgcn_mfma_f32_16x16x32_bf16(a0, *(const short8*)(br1 + 0),  c1, 0, 0, 0);
        c1 = __builtin_amdgcn_mfma_f32_16x16x32_bf16(a1, *(const short8*)(br1 + 32), c1, 0, 0, 0);
        c1 = __builtin_amdgcn_mfma_f32_16x16x32_bf16(a2, *(const short8*)(br1 + 64), c1, 0, 0, 0);
        const float bc0 = bqc[on0 * 16 + sn], bc1 = bqc[on1 * 16 + sn];
        float g0[4] = { gelu_exact(c0.x + bc0), gelu_exact(c0.y + bc0),
                        gelu_exact(c0.z + bc0), gelu_exact(c0.w + bc0) };
        float g1[4] = { gelu_exact(c1.x + bc1), gelu_exact(c1.y + bc1),
                        gelu_exact(c1.z + bc1), gelu_exact(c1.w + bc1) };
#pragma unroll
        for (int i = 0; i < 4; ++i) {
            Hb[(tm * 16 + quad * 4 + i) * 72 + on0 * 16 + sn] = f2bf(g0[i]);
            Hb[(tm * 16 + quad * 4 + i) * 72 + on1 * 16 + sn] = f2bf(g1[i]);
        }
    }
    __syncthreads();

    // ---- phase A proj GEMM -> qs (pre-scaled by SC)
    {
        const int tm = w & 3, cn = w >> 2;
        const unsigned short* hr = &Hb[(tm * 16 + sn) * 72 + quad * 8];
        short8 pa0 = *(const short8*)(hr + 0);
        short8 pa1 = *(const short8*)(hr + 32);
        const unsigned short* wr_ = &WpB[(cn * 16 + sn) * 72 + quad * 8];
        short8 pb0 = *(const short8*)(wr_ + 0);
        short8 pb1 = *(const short8*)(wr_ + 32);
        float4v pacc = zero;
        pacc = __builtin_amdgcn_mfma_f32_16x16x32_bf16(pa0, pb0, pacc, 0, 0, 0);
        pacc = __builtin_amdgcn_mfma_f32_16x16x32_bf16(pa1, pb1, pacc, 0, 0, 0);
        const float bpv = bqp[cn * 16 + sn];
        float v[4] = { (pacc.x + bpv) * SC, (pacc.y + bpv) * SC,
                       (pacc.z + bpv) * SC, (pacc.w + bpv) * SC };
#pragma unroll
        for (int i = 0; i < 4; ++i)
            qs[(tm * 16 + quad * 4 + i) * 40 + cn * 16 + sn] = f2bf(v[i]);
    }
    __syncthreads();

    // ---- phase B attention: wave w -> head h = w&1, row-tile rt = w>>1
    const int h = w & 1, rt = w >> 1;
    short8 aq = {0, 0, 0, 0, 0, 0, 0, 0};    // B-operand: zeros kill k>=16
    if (quad < 2)
        aq = *(const short8*)&qs[(rt * 16 + sn) * 40 + h * 16 + quad * 8];

    const unsigned short* kb = kbf + (size_t)b * T_LEN * 32 + h * 16 + quad * 8;
    const unsigned short* vb = vtbf + ((size_t)(b * 2 + h) * 16 + sn) * T_LEN + quad * 8;

    float4v yacc = zero;
    float l = 0.f;

#pragma unroll 1
    for (int s0 = 0; s0 < 1024; s0 += 64) {
        short8 ka0 = *(const short8*)(kb + (size_t)(s0 + sn) * 32);
        short8 ka1 = *(const short8*)(kb + (size_t)(s0 + 16 + sn) * 32);
        short8 ka2 = *(const short8*)(kb + (size_t)(s0 + 32 + sn) * 32);
        short8 ka3 = *(const short8*)(kb + (size_t)(s0 + 48 + sn) * 32);
        short8 bvA = *(const short8*)(vb + s0);
        short8 bvB = *(const short8*)(vb + s0 + 32);

        // S^T chunks: operand-swapped (A=K, B=q) -> C[row=s-off=4q+i][col=t=sn]
        float4v c0 = __builtin_amdgcn_mfma_f32_16x16x32_bf16(ka0, aq, zero, 0, 0, 0);
        float4v c1 = __builtin_amdgcn_mfma_f32_16x16x32_bf16(ka1, aq, zero, 0, 0, 0);
        float4v c2 = __builtin_amdgcn_mfma_f32_16x16x32_bf16(ka2, aq, zero, 0, 0, 0);
        float4v c3 = __builtin_amdgcn_mfma_f32_16x16x32_bf16(ka3, aq, zero, 0, 0, 0);

        float p00 = exp2f(c0.x), p01 = exp2f(c0.y), p02 = exp2f(c0.z), p03 = exp2f(c0.w);
        float p10 = exp2f(c1.x), p11 = exp2f(c1.y), p12 = exp2f(c1.z), p13 = exp2f(c1.w);
        float p20 = exp2f(c2.x), p21 = exp2f(c2.y), p22 = exp2f(c2.z), p23 = exp2f(c2.w);
        float p30 = exp2f(c3.x), p31 = exp2f(c3.y), p32 = exp2f(c3.z), p33 = exp2f(c3.w);

        l += ((p00 + p01) + (p02 + p03)) + ((p10 + p11) + (p12 + p13))
           + ((p20 + p21) + (p22 + p23)) + ((p30 + p31) + (p32 + p33));

        // PV A-frag = lane's own P values (perm baked into vtbf s-order)
        union { unsigned u[4]; short8 s8; } uA, uB;
        uA.u[0] = pk2bf(p00, p01); uA.u[1] = pk2bf(p02, p03);
        uA.u[2] = pk2bf(p10, p11); uA.u[3] = pk2bf(p12, p13);
        uB.u[0] = pk2bf(p20, p21); uB.u[1] = pk2bf(p22, p23);
        uB.u[2] = pk2bf(p30, p31); uB.u[3] = pk2bf(p32, p33);

        yacc = __builtin_amdgcn_mfma_f32_16x16x32_bf16(uA.s8, bvA, yacc, 0, 0, 0);
        yacc = __builtin_amdgcn_mfma_f32_16x16x32_bf16(uB.s8, bvB, yacc, 0, 0, 0);
    }

    // l reduction: quads hold disjoint s-subsets for t=sn -> sum across quads
    l += __shfl_xor(l, 16);
    l += __shfl_xor(l, 32);
    // re-index: yacc rows are t = quad*4+i; L[t] lives in lane t (quad 0)
    float li0 = __shfl(l, quad * 4 + 0);
    float li1 = __shfl(l, quad * 4 + 1);
    float li2 = __shfl(l, quad * 4 + 2);
    float li3 = __shfl(l, quad * 4 + 3);

    // normalized y -> sy (overlays dead Hb/WpB)
    float* sy = (float*)(smem + 24576);       // [64][32]
    {
        const int r0 = rt * 16 + quad * 4;
        sy[(r0 + 0) * 32 + h * 16 + sn] = yacc.x / li0;
        sy[(r0 + 1) * 32 + h * 16 + sn] = yacc.y / li1;
        sy[(r0 + 2) * 32 + h * 16 + sn] = yacc.z / li2;
        sy[(r0 + 3) * 32 + h * 16 + sn] = yacc.w / li3;
    }
    __syncthreads();

    // ---- phase C epilogue (overlays dead Abuf/WbT region)
    float* swc = (float*)(smem + 0);          // [32][36]
    float* swf = (float*)(smem + 4608);
    float* swm = (float*)(smem + 9216);
    float* sln = (float*)(smem + 13824);
    float* shn = (float*)(smem + 13952);      // [16][36]
    float* sgv = (float*)(smem + 16256);
    for (int i = tid; i < 1024; i += 512) {
        int r = i >> 5, cc = i & 31;
        swc[r * 36 + cc] = wcp[i];
        swf[r * 36 + cc] = wfc[i];
        swm[r * 36 + cc] = wmp[i];
    }
    if (tid < 32) sln[tid] = lnw[tid];
    __syncthreads();

    const int rl = tid >> 5, c = tid & 31;
    const float lnwc = sln[c];
#pragma unroll 1
    for (int p = 0; p < 4; ++p) {
        int r = p * 16 + rl;
        size_t row = (size_t)bf * T_LEN + t0 + r;
        float x1 = cd[row * 32 + c];
#pragma unroll
        for (int j4 = 0; j4 < 8; ++j4) {
            float4 yv = *(const float4*)&sy[r * 32 + j4 * 4];
            const float* wv = &swc[c * 36 + j4 * 4];
            x1 += wv[0] * yv.x + wv[1] * yv.y + wv[2] * yv.z + wv[3] * yv.w;
        }
        float s1 = x1, s2 = x1 * x1;
#pragma unroll
        for (int off = 16; off; off >>= 1) {
            s1 += __shfl_xor(s1, off);
            s2 += __shfl_xor(s2, off);
        }
        float mu = s1 * (1.0f / 32.0f);
        float var = s2 * (1.0f / 32.0f) - mu * mu;
        float hn = (x1 - mu) * rsqrtf(var + 1e-5f) * lnwc;
        shn[rl * 36 + c] = hn;
        float ga = 0.f;
#pragma unroll
        for (int j4 = 0; j4 < 8; ++j4) {
            float4 hv = *(const float4*)&shn[rl * 36 + j4 * 4];
            const float* wv = &swf[c * 36 + j4 * 4];
            ga += wv[0] * hv.x + wv[1] * hv.y + wv[2] * hv.z + wv[3] * hv.w;
        }
        float gv = gelu_exact(ga);
        sgv[rl * 36 + c] = gv;
        float oa = x1;
#pragma unroll
        for (int j4 = 0; j4 < 8; ++j4) {
            float4 gvv = *(const float4*)&sgv[rl * 36 + j4 * 4];
            const float* wv = &swm[c * 36 + j4 * 4];
            oa += wv[0] * gvv.x + wv[1] * gvv.y + wv[2] * gvv.z + wv[3] * gvv.w;
        }
        out[row * 32 + c] = oa;
    }
}

// ---------------------------------------------------------------------------
extern "C" void kernel_launch(void* const* d_in, const int* in_sizes, int n_in,
                              void* d_out, int out_size, void* d_ws, size_t ws_size,
                              hipStream_t stream) {
    const float* cd  = (const float*)d_in[0];
    const float* pkv = (const float*)d_in[1];
    const float* wqc = (const float*)d_in[2];
    const float* bqc = (const float*)d_in[3];
    const float* wqp = (const float*)d_in[4];
    const float* bqp = (const float*)d_in[5];
    const float* wkc = (const float*)d_in[6];
    const float* bkc = (const float*)d_in[7];
    const float* wkp = (const float*)d_in[8];
    const float* bkp = (const float*)d_in[9];
    const float* wvc = (const float*)d_in[10];
    const float* bvc = (const float*)d_in[11];
    const float* wvp = (const float*)d_in[12];
    const float* bvp = (const float*)d_in[13];
    const float* wcp = (const float*)d_in[14];
    const float* lnw = (const float*)d_in[15];
    const float* wfc = (const float*)d_in[16];
    const float* wmp = (const float*)d_in[17];

    // ws: kbf 0.5MB | vtbf 0.5MB
    unsigned short* kbf  = (unsigned short*)d_ws;
    unsigned short* vtbf = kbf + (size_t)8 * 1024 * 32;

    kv_tcl<<<512, 256, 0, stream>>>(pkv, wkc, bkc, wkp, bkp,
                                    wvc, bvc, wvp, bvp, kbf, vtbf);
    fused_qae<<<512, 512, 0, stream>>>(cd, wqc, bqc, wqp, bqp, kbf, vtbf,
                                       wcp, lnw, wfc, wmp, (float*)d_out);
}

// Round 17
// 133.357 us; speedup vs baseline: 1.0339x; 1.0339x over previous
//
#include <hip/hip_runtime.h>
#include <hip/hip_bf16.h>

// B=8, F=4, T=S=1024, C=32, C2=64, NH=2, HD=16
// Inputs fp32, output fp32. k/v staged bf16 in ws; q stays in LDS (fused).
#define T_LEN 1024

typedef __attribute__((ext_vector_type(8))) short short8;   // 8 bf16 = 4 VGPR
typedef __attribute__((ext_vector_type(4))) short short4v;
typedef __attribute__((ext_vector_type(4))) float float4v;

__device__ __forceinline__ float gelu_exact(float x) {
    return 0.5f * x * (1.0f + erff(x * 0.70710678118654752440f));
}
__device__ __forceinline__ unsigned short f2bf(float f) {   // RNE
    unsigned u = __float_as_uint(f);
    u += 0x7fffu + ((u >> 16) & 1u);
    return (unsigned short)(u >> 16);
}
__device__ __forceinline__ unsigned pk2bf(float a, float b) {  // (lo=a, hi=b)
    __hip_bfloat162 h = __float22bfloat162_rn(make_float2(a, b));
    unsigned u;
    __builtin_memcpy(&u, &h, 4);
    return u;
}
// raw v_exp_f32 (exp2): scores |x|<1 here, far from OCML's fixup range
__device__ __forceinline__ float fexp2(float x) { return __builtin_amdgcn_exp2f(x); }

// ---------------------------------------------------------------------------
// kv_tcl: k/v TCL, 512 blocks x 256 thr, 32-row tiles.
// [0,256): k -> kbf [8][1024][32]; [256,512): v -> vtbf [8][2][16][1024]
// with PV-perm s-order inside each 32-block: slot kp holds s-offset o where
// kp = (r>>2)<<3 | hi<<2 | (r&3), hi=o>>4, r=o&15  (bijection; matches the
// attention PV A-frag = lane's own QK output registers).
// ---------------------------------------------------------------------------
__global__ __launch_bounds__(256) void kv_tcl(
    const float* __restrict__ pkv,
    const float* __restrict__ wkc, const float* __restrict__ bkc,
    const float* __restrict__ wkp, const float* __restrict__ bkp,
    const float* __restrict__ wvc, const float* __restrict__ bvc,
    const float* __restrict__ wvp, const float* __restrict__ bvp,
    unsigned short* __restrict__ kbf, unsigned short* __restrict__ vtbf)
{
    __shared__ __align__(16) unsigned short Abuf[32 * 96];
    __shared__ __align__(16) unsigned short WbT[64 * 96];
    __shared__ __align__(16) unsigned short Hb[32 * 72];
    __shared__ __align__(16) unsigned short WpB[32 * 72];

    const int tid = threadIdx.x;
    const int gb = blockIdx.x;

    const float *wc, *bc, *wp, *bp;
    unsigned short* outb;
    int n, mode;
    if (gb < 256) { n = gb >> 5;         wc = wkc; bc = bkc; wp = wkp; bp = bkp; outb = kbf;  mode = 0; }
    else          { n = (gb - 256) >> 5; wc = wvc; bc = bvc; wp = wvp; bp = bvp; outb = vtbf; mode = 1; }
    const int t0 = (gb & 31) * 32;

#pragma unroll
    for (int it = 0; it < 3; ++it) {
        int s = (tid + it * 256) >> 3;
        int sub = tid & 7;
        int t = s / 3, tap = s - t * 3;
        int tau = t0 + t - 2 + tap;
        float4 xv = make_float4(0.f, 0.f, 0.f, 0.f);
        if (tau >= 0) xv = *(const float4*)&pkv[((size_t)n * T_LEN + tau) * 32 + sub * 4];
        short4v pk = { (short)f2bf(xv.x), (short)f2bf(xv.y),
                       (short)f2bf(xv.z), (short)f2bf(xv.w) };
        *(short4v*)&Abuf[t * 96 + tap * 32 + sub * 4] = pk;
    }
#pragma unroll
    for (int it = 0; it < 6; ++it) {
        int i4 = tid + it * 256;
        int idx = i4 * 4;
        int o = idx / 96, r = idx - o * 96;
        float4 w4 = *(const float4*)&wc[idx];
        float we[4] = { w4.x, w4.y, w4.z, w4.w };
#pragma unroll
        for (int e = 0; e < 4; ++e) {
            int re = r + e, c = re / 3, tap = re - c * 3;
            WbT[o * 96 + tap * 32 + c] = f2bf(we[e]);
        }
    }
#pragma unroll
    for (int it = 0; it < 2; ++it) {
        int i4 = tid + it * 256;
        int idx = i4 * 4;
        int c = idx >> 6, o = idx & 63;
        float4 w4 = *(const float4*)&wp[idx];
        short4v pk = { (short)f2bf(w4.x), (short)f2bf(w4.y),
                       (short)f2bf(w4.z), (short)f2bf(w4.w) };
        *(short4v*)&WpB[c * 72 + o] = pk;
    }

    const int w = tid >> 6;
    const int ln = tid & 63;
    const int sn = ln & 15;
    const int quad = ln >> 4;

    const float bcv = bc[w * 16 + sn];
    const int tmw = w & 1, cnw = w >> 1;
    const float bpv = bp[cnw * 16 + sn];

    __syncthreads();

    short8 b0 = *(const short8*)&WbT[(w * 16 + sn) * 96 + 0  + quad * 8];
    short8 b1 = *(const short8*)&WbT[(w * 16 + sn) * 96 + 32 + quad * 8];
    short8 b2 = *(const short8*)&WbT[(w * 16 + sn) * 96 + 64 + quad * 8];
    float4v zero = { 0.f, 0.f, 0.f, 0.f };
    float4v acc[2] = { zero, zero };
#pragma unroll
    for (int tm = 0; tm < 2; ++tm) {
        const unsigned short* ar = &Abuf[(tm * 16 + sn) * 96 + quad * 8];
        short8 a0 = *(const short8*)(ar + 0);
        short8 a1 = *(const short8*)(ar + 32);
        short8 a2 = *(const short8*)(ar + 64);
        acc[tm] = __builtin_amdgcn_mfma_f32_16x16x32_bf16(a0, b0, acc[tm], 0, 0, 0);
        acc[tm] = __builtin_amdgcn_mfma_f32_16x16x32_bf16(a1, b1, acc[tm], 0, 0, 0);
        acc[tm] = __builtin_amdgcn_mfma_f32_16x16x32_bf16(a2, b2, acc[tm], 0, 0, 0);
    }
#pragma unroll
    for (int tm = 0; tm < 2; ++tm) {
        float ge[4];
        ge[0] = gelu_exact(acc[tm].x + bcv);
        ge[1] = gelu_exact(acc[tm].y + bcv);
        ge[2] = gelu_exact(acc[tm].z + bcv);
        ge[3] = gelu_exact(acc[tm].w + bcv);
#pragma unroll
        for (int i = 0; i < 4; ++i)
            Hb[(tm * 16 + quad * 4 + i) * 72 + w * 16 + sn] = f2bf(ge[i]);
    }

    __syncthreads();

    const unsigned short* hr = &Hb[(tmw * 16 + sn) * 72 + quad * 8];
    short8 pa0 = *(const short8*)(hr + 0);
    short8 pa1 = *(const short8*)(hr + 32);
    short8 pb0 = *(const short8*)&WpB[(cnw * 16 + sn) * 72 + quad * 8];
    short8 pb1 = *(const short8*)&WpB[(cnw * 16 + sn) * 72 + 32 + quad * 8];
    float4v pacc = zero;
    pacc = __builtin_amdgcn_mfma_f32_16x16x32_bf16(pa0, pb0, pacc, 0, 0, 0);
    pacc = __builtin_amdgcn_mfma_f32_16x16x32_bf16(pa1, pb1, pacc, 0, 0, 0);

    float v[4] = { pacc.x + bpv, pacc.y + bpv, pacc.z + bpv, pacc.w + bpv };
#pragma unroll
    for (int i = 0; i < 4; ++i) {
        int t = tmw * 16 + quad * 4 + i;      // 0..31
        int c = cnw * 16 + sn;
        if (mode == 0) {
            outb[((size_t)n * T_LEN + t0 + t) * 32 + c] = f2bf(v[i]);
        } else {
            int hi = t >> 4, r = t & 15;
            int kp = ((r >> 2) << 3) | (hi << 2) | (r & 3);
            outb[((size_t)(n * 2 + cnw) * 16 + sn) * T_LEN + t0 + kp] = f2bf(v[i]);
        }
    }
}

// ---------------------------------------------------------------------------
// fused_qae v5: = v4 (register-P, zero LDS in loop) with two inner-loop
// changes: (1) exp2f -> __builtin_amdgcn_exp2f (raw v_exp_f32; OCML's
// multi-instr exp2 wrapper was the dominant VALU cost suspect);
// (2) #pragma unroll 2 on the s-loop for load/compute overlap.
// ---------------------------------------------------------------------------
__global__ __launch_bounds__(512) void fused_qae(
    const float* __restrict__ cd,
    const float* __restrict__ wqc, const float* __restrict__ bqc,
    const float* __restrict__ wqp, const float* __restrict__ bqp,
    const unsigned short* __restrict__ kbf,
    const unsigned short* __restrict__ vtbf,
    const float* __restrict__ wcp, const float* __restrict__ lnw,
    const float* __restrict__ wfc, const float* __restrict__ wmp,
    float* __restrict__ out)
{
    __shared__ __align__(16) char smem[43520];
    unsigned short* Abuf = (unsigned short*)(smem);
    unsigned short* WbT  = (unsigned short*)(smem + 12288);
    unsigned short* Hb   = (unsigned short*)(smem + 24576);
    unsigned short* WpB  = (unsigned short*)(smem + 33792);
    unsigned short* qs   = (unsigned short*)(smem + 38400);

    const int tid = threadIdx.x;
    const int bf = blockIdx.x >> 4;
    const int tt = blockIdx.x & 15;
    const int t0 = tt * 64;
    const int b = bf >> 2;
    const float SC = 0.36067376022224085f;    // 0.25 * log2(e)

    // ---- phase A staging (512 threads)
#pragma unroll
    for (int it = 0; it < 3; ++it) {
        int idx = tid + it * 512;             // 0..1535
        int s = idx >> 3;                     // 0..191
        int sub = idx & 7;
        int t = s / 3, tap = s - t * 3;
        int tau = t0 + t - 2 + tap;
        float4 xv = make_float4(0.f, 0.f, 0.f, 0.f);
        if (tau >= 0) xv = *(const float4*)&cd[((size_t)bf * T_LEN + tau) * 32 + sub * 4];
        short4v pk = { (short)f2bf(xv.x), (short)f2bf(xv.y),
                       (short)f2bf(xv.z), (short)f2bf(xv.w) };
        *(short4v*)&Abuf[t * 96 + tap * 32 + sub * 4] = pk;
    }
#pragma unroll
    for (int it = 0; it < 3; ++it) {
        int i4 = tid + it * 512;              // 0..1535
        int idx = i4 * 4;
        int o = idx / 96, r = idx - o * 96;
        float4 w4 = *(const float4*)&wqc[idx];
        float we[4] = { w4.x, w4.y, w4.z, w4.w };
#pragma unroll
        for (int e = 0; e < 4; ++e) {
            int re = r + e, c = re / 3, tap = re - c * 3;
            WbT[o * 96 + tap * 32 + c] = f2bf(we[e]);
        }
    }
    {
        int idx = tid * 4;                    // 512 float4s
        int c = idx >> 6, o = idx & 63;
        float4 w4 = *(const float4*)&wqp[idx];
        short4v pk = { (short)f2bf(w4.x), (short)f2bf(w4.y),
                       (short)f2bf(w4.z), (short)f2bf(w4.w) };
        *(short4v*)&WpB[c * 72 + o] = pk;
    }

    const int w = tid >> 6;       // wave 0..7
    const int ln = tid & 63;
    const int sn = ln & 15;
    const int quad = ln >> 4;
    const float4v zero = { 0.f, 0.f, 0.f, 0.f };

    __syncthreads();

    // ---- phase A conv GEMM: wave w -> t-tile w&3, o-tiles {w>>2, w>>2+2}
    {
        const int tm = w & 3;
        const int on0 = w >> 2, on1 = on0 + 2;
        const unsigned short* ar = &Abuf[(tm * 16 + sn) * 96 + quad * 8];
        short8 a0 = *(const short8*)(ar + 0);
        short8 a1 = *(const short8*)(ar + 32);
        short8 a2 = *(const short8*)(ar + 64);
        const unsigned short* br0 = &WbT[(on0 * 16 + sn) * 96 + quad * 8];
        const unsigned short* br1 = &WbT[(on1 * 16 + sn) * 96 + quad * 8];
        float4v c0 = zero, c1 = zero;
        c0 = __builtin_amdgcn_mfma_f32_16x16x32_bf16(a0, *(const short8*)(br0 + 0),  c0, 0, 0, 0);
        c0 = __builtin_amdgcn_mfma_f32_16x16x32_bf16(a1, *(const short8*)(br0 + 32), c0, 0, 0, 0);
        c0 = __builtin_amdgcn_mfma_f32_16x16x32_bf16(a2, *(const short8*)(br0 + 64), c0, 0, 0, 0);
        c1 = __builtin_amdgcn_mfma_f32_16x16x32_bf16(a0, *(const short8*)(br1 + 0),  c1, 0, 0, 0);
        c1 = __builtin_amdgcn_mfma_f32_16x16x32_bf16(a1, *(const short8*)(br1 + 32), c1, 0, 0, 0);
        c1 = __builtin_amdgcn_mfma_f32_16x16x32_bf16(a2, *(const short8*)(br1 + 64), c1, 0, 0, 0);
        const float bc0 = bqc[on0 * 16 + sn], bc1 = bqc[on1 * 16 + sn];
        float g0[4] = { gelu_exact(c0.x + bc0), gelu_exact(c0.y + bc0),
                        gelu_exact(c0.z + bc0), gelu_exact(c0.w + bc0) };
        float g1[4] = { gelu_exact(c1.x + bc1), gelu_exact(c1.y + bc1),
                        gelu_exact(c1.z + bc1), gelu_exact(c1.w + bc1) };
#pragma unroll
        for (int i = 0; i < 4; ++i) {
            Hb[(tm * 16 + quad * 4 + i) * 72 + on0 * 16 + sn] = f2bf(g0[i]);
            Hb[(tm * 16 + quad * 4 + i) * 72 + on1 * 16 + sn] = f2bf(g1[i]);
        }
    }
    __syncthreads();

    // ---- phase A proj GEMM -> qs (pre-scaled by SC)
    {
        const int tm = w & 3, cn = w >> 2;
        const unsigned short* hr = &Hb[(tm * 16 + sn) * 72 + quad * 8];
        short8 pa0 = *(const short8*)(hr + 0);
        short8 pa1 = *(const short8*)(hr + 32);
        const unsigned short* wr_ = &WpB[(cn * 16 + sn) * 72 + quad * 8];
        short8 pb0 = *(const short8*)(wr_ + 0);
        short8 pb1 = *(const short8*)(wr_ + 32);
        float4v pacc = zero;
        pacc = __builtin_amdgcn_mfma_f32_16x16x32_bf16(pa0, pb0, pacc, 0, 0, 0);
        pacc = __builtin_amdgcn_mfma_f32_16x16x32_bf16(pa1, pb1, pacc, 0, 0, 0);
        const float bpv = bqp[cn * 16 + sn];
        float v[4] = { (pacc.x + bpv) * SC, (pacc.y + bpv) * SC,
                       (pacc.z + bpv) * SC, (pacc.w + bpv) * SC };
#pragma unroll
        for (int i = 0; i < 4; ++i)
            qs[(tm * 16 + quad * 4 + i) * 40 + cn * 16 + sn] = f2bf(v[i]);
    }
    __syncthreads();

    // ---- phase B attention: wave w -> head h = w&1, row-tile rt = w>>1
    const int h = w & 1, rt = w >> 1;
    short8 aq = {0, 0, 0, 0, 0, 0, 0, 0};    // B-operand: zeros kill k>=16
    if (quad < 2)
        aq = *(const short8*)&qs[(rt * 16 + sn) * 40 + h * 16 + quad * 8];

    const unsigned short* kb = kbf + (size_t)b * T_LEN * 32 + h * 16 + quad * 8;
    const unsigned short* vb = vtbf + ((size_t)(b * 2 + h) * 16 + sn) * T_LEN + quad * 8;

    float4v yacc = zero;
    float l = 0.f;

#pragma unroll 2
    for (int s0 = 0; s0 < 1024; s0 += 64) {
        short8 ka0 = *(const short8*)(kb + (size_t)(s0 + sn) * 32);
        short8 ka1 = *(const short8*)(kb + (size_t)(s0 + 16 + sn) * 32);
        short8 ka2 = *(const short8*)(kb + (size_t)(s0 + 32 + sn) * 32);
        short8 ka3 = *(const short8*)(kb + (size_t)(s0 + 48 + sn) * 32);
        short8 bvA = *(const short8*)(vb + s0);
        short8 bvB = *(const short8*)(vb + s0 + 32);

        // S^T chunks: operand-swapped (A=K, B=q) -> C[row=s-off=4q+i][col=t=sn]
        float4v c0 = __builtin_amdgcn_mfma_f32_16x16x32_bf16(ka0, aq, zero, 0, 0, 0);
        float4v c1 = __builtin_amdgcn_mfma_f32_16x16x32_bf16(ka1, aq, zero, 0, 0, 0);
        float4v c2 = __builtin_amdgcn_mfma_f32_16x16x32_bf16(ka2, aq, zero, 0, 0, 0);
        float4v c3 = __builtin_amdgcn_mfma_f32_16x16x32_bf16(ka3, aq, zero, 0, 0, 0);

        float p00 = fexp2(c0.x), p01 = fexp2(c0.y), p02 = fexp2(c0.z), p03 = fexp2(c0.w);
        float p10 = fexp2(c1.x), p11 = fexp2(c1.y), p12 = fexp2(c1.z), p13 = fexp2(c1.w);
        float p20 = fexp2(c2.x), p21 = fexp2(c2.y), p22 = fexp2(c2.z), p23 = fexp2(c2.w);
        float p30 = fexp2(c3.x), p31 = fexp2(c3.y), p32 = fexp2(c3.z), p33 = fexp2(c3.w);

        l += ((p00 + p01) + (p02 + p03)) + ((p10 + p11) + (p12 + p13))
           + ((p20 + p21) + (p22 + p23)) + ((p30 + p31) + (p32 + p33));

        // PV A-frag = lane's own P values (perm baked into vtbf s-order)
        union { unsigned u[4]; short8 s8; } uA, uB;
        uA.u[0] = pk2bf(p00, p01); uA.u[1] = pk2bf(p02, p03);
        uA.u[2] = pk2bf(p10, p11); uA.u[3] = pk2bf(p12, p13);
        uB.u[0] = pk2bf(p20, p21); uB.u[1] = pk2bf(p22, p23);
        uB.u[2] = pk2bf(p30, p31); uB.u[3] = pk2bf(p32, p33);

        yacc = __builtin_amdgcn_mfma_f32_16x16x32_bf16(uA.s8, bvA, yacc, 0, 0, 0);
        yacc = __builtin_amdgcn_mfma_f32_16x16x32_bf16(uB.s8, bvB, yacc, 0, 0, 0);
    }

    // l reduction: quads hold disjoint s-subsets for t=sn -> sum across quads
    l += __shfl_xor(l, 16);
    l += __shfl_xor(l, 32);
    // re-index: yacc rows are t = quad*4+i; L[t] lives in lane t (quad 0/1)
    float li0 = __shfl(l, quad * 4 + 0);
    float li1 = __shfl(l, quad * 4 + 1);
    float li2 = __shfl(l, quad * 4 + 2);
    float li3 = __shfl(l, quad * 4 + 3);

    // normalized y -> sy (overlays dead Hb/WpB)
    float* sy = (float*)(smem + 24576);       // [64][32]
    {
        const int r0 = rt * 16 + quad * 4;
        sy[(r0 + 0) * 32 + h * 16 + sn] = yacc.x / li0;
        sy[(r0 + 1) * 32 + h * 16 + sn] = yacc.y / li1;
        sy[(r0 + 2) * 32 + h * 16 + sn] = yacc.z / li2;
        sy[(r0 + 3) * 32 + h * 16 + sn] = yacc.w / li3;
    }
    __syncthreads();

    // ---- phase C epilogue (overlays dead Abuf/WbT region)
    float* swc = (float*)(smem + 0);          // [32][36]
    float* swf = (float*)(smem + 4608);
    float* swm = (float*)(smem + 9216);
    float* sln = (float*)(smem + 13824);
    float* shn = (float*)(smem + 13952);      // [16][36]
    float* sgv = (float*)(smem + 16256);
    for (int i = tid; i < 1024; i += 512) {
        int r = i >> 5, cc = i & 31;
        swc[r * 36 + cc] = wcp[i];
        swf[r * 36 + cc] = wfc[i];
        swm[r * 36 + cc] = wmp[i];
    }
    if (tid < 32) sln[tid] = lnw[tid];
    __syncthreads();

    const int rl = tid >> 5, c = tid & 31;
    const float lnwc = sln[c];
#pragma unroll 1
    for (int p = 0; p < 4; ++p) {
        int r = p * 16 + rl;
        size_t row = (size_t)bf * T_LEN + t0 + r;
        float x1 = cd[row * 32 + c];
#pragma unroll
        for (int j4 = 0; j4 < 8; ++j4) {
            float4 yv = *(const float4*)&sy[r * 32 + j4 * 4];
            const float* wv = &swc[c * 36 + j4 * 4];
            x1 += wv[0] * yv.x + wv[1] * yv.y + wv[2] * yv.z + wv[3] * yv.w;
        }
        float s1 = x1, s2 = x1 * x1;
#pragma unroll
        for (int off = 16; off; off >>= 1) {
            s1 += __shfl_xor(s1, off);
            s2 += __shfl_xor(s2, off);
        }
        float mu = s1 * (1.0f / 32.0f);
        float var = s2 * (1.0f / 32.0f) - mu * mu;
        float hn = (x1 - mu) * rsqrtf(var + 1e-5f) * lnwc;
        shn[rl * 36 + c] = hn;
        float ga = 0.f;
#pragma unroll
        for (int j4 = 0; j4 < 8; ++j4) {
            float4 hv = *(const float4*)&shn[rl * 36 + j4 * 4];
            const float* wv = &swf[c * 36 + j4 * 4];
            ga += wv[0] * hv.x + wv[1] * hv.y + wv[2] * hv.z + wv[3] * hv.w;
        }
        float gv = gelu_exact(ga);
        sgv[rl * 36 + c] = gv;
        float oa = x1;
#pragma unroll
        for (int j4 = 0; j4 < 8; ++j4) {
            float4 gvv = *(const float4*)&sgv[rl * 36 + j4 * 4];
            const float* wv = &swm[c * 36 + j4 * 4];
            oa += wv[0] * gvv.x + wv[1] * gvv.y + wv[2] * gvv.z + wv[3] * gvv.w;
        }
        out[row * 32 + c] = oa;
    }
}

// ---------------------------------------------------------------------------
extern "C" void kernel_launch(void* const* d_in, const int* in_sizes, int n_in,
                              void* d_out, int out_size, void* d_ws, size_t ws_size,
                              hipStream_t stream) {
    const float* cd  = (const float*)d_in[0];
    const float* pkv = (const float*)d_in[1];
    const float* wqc = (const float*)d_in[2];
    const float* bqc = (const float*)d_in[3];
    const float* wqp = (const float*)d_in[4];
    const float* bqp = (const float*)d_in[5];
    const float* wkc = (const float*)d_in[6];
    const float* bkc = (const float*)d_in[7];
    const float* wkp = (const float*)d_in[8];
    const float* bkp = (const float*)d_in[9];
    const float* wvc = (const float*)d_in[10];
    const float* bvc = (const float*)d_in[11];
    const float* wvp = (const float*)d_in[12];
    const float* bvp = (const float*)d_in[13];
    const float* wcp = (const float*)d_in[14];
    const float* lnw = (const float*)d_in[15];
    const float* wfc = (const float*)d_in[16];
    const float* wmp = (const float*)d_in[17];

    // ws: kbf 0.5MB | vtbf 0.5MB
    unsigned short* kbf  = (unsigned short*)d_ws;
    unsigned short* vtbf = kbf + (size_t)8 * 1024 * 32;

    kv_tcl<<<512, 256, 0, stream>>>(pkv, wkc, bkc, wkp, bkp,
                                    wvc, bvc, wvp, bvp, kbf, vtbf);
    fused_qae<<<512, 512, 0, stream>>>(cd, wqc, bqc, wqp, bqp, kbf, vtbf,
                                       wcp, lnw, wfc, wmp, (float*)d_out);
}